// Round 5
// baseline (2499.150 us; speedup 1.0000x reference)
//
#include <hip/hip_runtime.h>
#include <stdint.h>

// Vector quantizer, bit-exact emulation of the numpy-f32 reference pipeline:
//   Sx[n] = np.sum(x_flat*x_flat, 1)   (numpy pairwise_sum, n=256)
//   M     = x_flat @ cb.T              (BLAS: sequential FMA over c ascending)
//   dist  = fl(fl(Sx - 2M) + Se),  idx = argmin (first min)
// x (16,256,1500) f32, codebook (2048,256) f32.
// out = [quantized (B,C,T) | indices (B,1,T) as float | loss] f32.
//
// Perf structure: xT = transpose(x) in d_out scratch; fused GEMM+argmin,
// 64-row x 256-code tiles, 8x8 micro-tile, double-buffered LDS with
// global_load_lds(16B) issued BEFORE each compute phase (one barrier/stage,
// vmcnt drain hidden under 2048 FMAs), XOR-swizzled conflict-free
// ds_read_b128, K split 4-ways, merged via u64 (dist_bits<<32|k) atomicMin.

#define B_DIM 16
#define C_DIM 256
#define T_DIM 1500
#define K_CODES 2048
#define N_ROWS (B_DIM * T_DIM)               // 24000
#define TOTAL_ELEMS (B_DIM * C_DIM * T_DIM)  // 6144000

#define TM 64        // t-rows per argmin block
#define TKC 256      // codes per chunk
#define CS 32        // c per step
#define KSLICE 512   // codes per block (4 slices)
#define NST 16       // stages = (KSLICE/TKC) * (C_DIM/CS)
#define OT 64        // t per output block

__device__ __forceinline__ void gl_lds16(const float* g, float* l) {
    __builtin_amdgcn_global_load_lds(
        (const __attribute__((address_space(1))) void*)(uintptr_t)g,
        (__attribute__((address_space(3))) void*)(uintptr_t)l, 16, 0, 0);
}

// ---------------- kernel T: x (B,C,T) -> xT (B,T,C) in d_out scratch --------
__global__ __launch_bounds__(256) void vq_transpose(const float* __restrict__ x,
                                                    float* __restrict__ xT) {
    __shared__ float tile[32][33];
    const int b = blockIdx.z;
    const int t0 = blockIdx.x * 32;
    const int c0 = blockIdx.y * 32;
    const int tx = threadIdx.x & 31;
    const int ty = threadIdx.x >> 5;          // 0..7
#pragma unroll
    for (int q = 0; q < 4; ++q) {
        const int c = c0 + ty * 4 + q;
        int t = t0 + tx; if (t >= T_DIM) t = T_DIM - 1;
        tile[ty * 4 + q][tx] = x[((size_t)b * C_DIM + c) * T_DIM + t];
    }
    __syncthreads();
#pragma unroll
    for (int q = 0; q < 4; ++q) {
        const int t = t0 + ty * 4 + q;
        if (t < T_DIM)
            xT[((size_t)b * T_DIM + t) * C_DIM + c0 + tx] = tile[tx][ty * 4 + q];
    }
}

// ---------------- kernel A: Se[k] = np-pairwise sum of cb row squares -------
__global__ __launch_bounds__(256) void vq_se(const float* __restrict__ cb,
                                             float* __restrict__ Se) {
    const int k = blockIdx.x * 256 + threadIdx.x;
    if (k >= K_CODES) return;
    const float* row = cb + (size_t)k * C_DIM;
    float h[2];
#pragma unroll
    for (int half = 0; half < 2; ++half) {
        const float* a = row + half * 128;
        float r[8];
#pragma unroll
        for (int j = 0; j < 8; ++j) r[j] = __fmul_rn(a[j], a[j]);
        for (int i = 8; i < 128; i += 8)
#pragma unroll
            for (int j = 0; j < 8; ++j)
                r[j] = __fadd_rn(r[j], __fmul_rn(a[i + j], a[i + j]));
        h[half] = __fadd_rn(
            __fadd_rn(__fadd_rn(r[0], r[1]), __fadd_rn(r[2], r[3])),
            __fadd_rn(__fadd_rn(r[4], r[5]), __fadd_rn(r[6], r[7])));
    }
    Se[k] = __fadd_rn(h[0], h[1]);
}

// ---------------- kernel B: Sx[n] from xT rows (same pairwise order) --------
__global__ __launch_bounds__(256) void vq_sx(const float* __restrict__ xT,
                                             float* __restrict__ Sx) {
    const int n = blockIdx.x * 256 + threadIdx.x;
    if (n >= N_ROWS) return;
    const float* row = xT + (size_t)n * C_DIM;
    float h[2];
#pragma unroll
    for (int half = 0; half < 2; ++half) {
        const float* a = row + half * 128;
        float r[8];
#pragma unroll
        for (int j = 0; j < 8; ++j) r[j] = __fmul_rn(a[j], a[j]);
        for (int i = 8; i < 128; i += 8)
#pragma unroll
            for (int j = 0; j < 8; ++j)
                r[j] = __fadd_rn(r[j], __fmul_rn(a[i + j], a[i + j]));
        h[half] = __fadd_rn(
            __fadd_rn(__fadd_rn(r[0], r[1]), __fadd_rn(r[2], r[3])),
            __fadd_rn(__fadd_rn(r[4], r[5]), __fadd_rn(r[6], r[7])));
    }
    Sx[n] = __fadd_rn(h[0], h[1]);
}

// ---------------- kernel I: init u64 argmin slots ---------------------------
__global__ void vq_init(unsigned long long* __restrict__ slots) {
    const int n = blockIdx.x * 256 + threadIdx.x;
    if (n < N_ROWS) slots[n] = ~0ull;
}

// ---- staging/compute macros (distinct LDS array names => provable no-alias)
#define STAGE_X(XS, C0_) do {                                                  \
    _Pragma("unroll")                                                          \
    for (int p_ = 0; p_ < 2; ++p_) {                                           \
        const int A_ = p_ * 256 + tid;                                         \
        const int r_ = A_ >> 3, slot_ = A_ & 7;                                \
        const int g4_ = slot_ ^ ((r_ >> 3) & 7);                               \
        int t_ = t0 + r_; if (t_ >= T_DIM) t_ = T_DIM - 1;                     \
        gl_lds16(xTb + (size_t)t_ * C_DIM + (C0_) + g4_ * 4, &XS[A_ * 4]);     \
    } } while (0)

#define STAGE_CB(CSARR, KC_, C0_) do {                                         \
    _Pragma("unroll")                                                          \
    for (int i_ = 0; i_ < 8; ++i_) {                                           \
        const int A_ = i_ * 256 + tid;                                         \
        const int kk_ = A_ >> 3, slot_ = A_ & 7;                               \
        const int g4_ = slot_ ^ ((kk_ >> 3) & 7);                              \
        gl_lds16(cb + (size_t)(k0 + (KC_) + kk_) * C_DIM + (C0_) + g4_ * 4,    \
                 &CSARR[A_ * 4]);                                              \
    } } while (0)

#define COMPUTE(XS, CSARR) do {                                                \
    _Pragma("unroll")                                                          \
    for (int g_ = 0; g_ < 8; ++g_) {                                           \
        float4 cv[8];                                                          \
        _Pragma("unroll")                                                      \
        for (int j_ = 0; j_ < 8; ++j_)                                         \
            cv[j_] = *reinterpret_cast<const float4*>(                         \
                &CSARR[(tcol * 8 + j_) * CS + ((g_ ^ (tcol & 7)) << 2)]);      \
        _Pragma("unroll")                                                      \
        for (int i_ = 0; i_ < 8; ++i_) {                                       \
            const float4 xv = *reinterpret_cast<const float4*>(                \
                &XS[(tr * 8 + i_) * CS + ((g_ ^ tr) << 2)]);                   \
            _Pragma("unroll")                                                  \
            for (int j_ = 0; j_ < 8; ++j_) {                                   \
                acc[i_][j_] = fmaf(xv.x, cv[j_].x, acc[i_][j_]);               \
                acc[i_][j_] = fmaf(xv.y, cv[j_].y, acc[i_][j_]);               \
                acc[i_][j_] = fmaf(xv.z, cv[j_].z, acc[i_][j_]);               \
                acc[i_][j_] = fmaf(xv.w, cv[j_].w, acc[i_][j_]);               \
            }                                                                  \
        }                                                                      \
    } } while (0)

#define SCORE(KCHUNK_) do {                                                    \
    _Pragma("unroll")                                                          \
    for (int j_ = 0; j_ < 8; ++j_) {                                           \
        const int kg_ = k0 + (KCHUNK_) * TKC + tcol * 8 + j_;                  \
        _Pragma("unroll")                                                      \
        for (int i_ = 0; i_ < 8; ++i_) {                                       \
            const float s_ = __fadd_rn(                                        \
                __fsub_rn(sxr[i_], __fmul_rn(2.0f, acc[i_][j_])), evr[j_]);    \
            if (s_ < m1[i_]) { m1[i_] = s_; k1[i_] = kg_; }                    \
            acc[i_][j_] = 0.f;                                                 \
        }                                                                      \
    } } while (0)

// ---------------- kernel C: fused GEMM + argmin (bit-exact np-f32) ----------
// grid (24 t-tiles, 16 b, 4 k-slices), 256 threads, 2-phase LDS pipeline.
__global__ __launch_bounds__(256, 2) void vq_argmin(
    const float* __restrict__ xT, const float* __restrict__ cb,
    const float* __restrict__ Se, const float* __restrict__ Sx,
    unsigned long long* __restrict__ slots) {
    __shared__ float xs0[TM * CS], xs1[TM * CS];     // 8 KB each
    __shared__ float cs0[TKC * CS], cs1[TKC * CS];   // 32 KB each

    const int tid = threadIdx.x;
    const int t0 = blockIdx.x * TM;
    const int b = blockIdx.y;
    const int k0 = blockIdx.z * KSLICE;
    const int tr = tid & 7;
    const int tcol = tid >> 3;           // 0..31

    const float* xTb = xT + (size_t)b * T_DIM * C_DIM;

    float sxr[8];
#pragma unroll
    for (int i = 0; i < 8; ++i) {
        const int t = t0 + tr * 8 + i;
        sxr[i] = (t < T_DIM) ? Sx[b * T_DIM + t] : 0.f;
    }

    float evr[8];
    float m1[8];
    int k1[8];
    float acc[8][8];
#pragma unroll
    for (int i = 0; i < 8; ++i) {
        m1[i] = 1e30f; k1[i] = 0x7fffffff;
#pragma unroll
        for (int j = 0; j < 8; ++j) acc[i][j] = 0.f;
    }

    // prologue: stage 0 -> buf0
    STAGE_X(xs0, 0);
    STAGE_CB(cs0, 0, 0);
    __syncthreads();

#pragma unroll 1
    for (int sp = 0; sp < NST; sp += 2) {
        const int s1 = sp + 1;
        // ---- even stage sp (buf0); prefetch s1 -> buf1
        {
            const int kc1 = (s1 >> 3) * TKC, c01 = (s1 & 7) * CS;
            STAGE_X(xs1, c01);
            STAGE_CB(cs1, kc1, c01);
            if ((sp & 7) == 0) {   // chunk start: Se -> regs (hidden latency)
                const float4 e0 = *reinterpret_cast<const float4*>(
                    Se + k0 + (sp >> 3) * TKC + tcol * 8);
                const float4 e1 = *reinterpret_cast<const float4*>(
                    Se + k0 + (sp >> 3) * TKC + tcol * 8 + 4);
                evr[0] = e0.x; evr[1] = e0.y; evr[2] = e0.z; evr[3] = e0.w;
                evr[4] = e1.x; evr[5] = e1.y; evr[6] = e1.z; evr[7] = e1.w;
            }
            COMPUTE(xs0, cs0);
            __syncthreads();       // drains buf1 loads (issued ~2048 FMAs ago)
        }
        // ---- odd stage s1 (buf1); prefetch sp+2 -> buf0
        {
            if (sp + 2 < NST) {
                const int s2 = sp + 2;
                const int kc2 = (s2 >> 3) * TKC, c02 = (s2 & 7) * CS;
                STAGE_X(xs0, c02);
                STAGE_CB(cs0, kc2, c02);
            }
            COMPUTE(xs1, cs1);
            if ((s1 & 7) == 7) SCORE(s1 >> 3);   // end of chunk (s1 = 7, 15)
            __syncthreads();
        }
    }

    // ---- cross-thread merge, transposed layout (conflict-free), alias LDS
    float* redm = cs0;                         // [32][64]
    int* redk = reinterpret_cast<int*>(cs1);   // [32][64]
#pragma unroll
    for (int i = 0; i < 8; ++i) {
        const int r = tr * 8 + i;
        redm[tcol * 64 + r] = m1[i];
        redk[tcol * 64 + r] = k1[i];
    }
    __syncthreads();
    if (tid < TM) {
        const int r = tid;
        float bm = 1e30f;
        int bk = 0x7fffffff;
        for (int tc = 0; tc < 32; ++tc) {
            const float c1 = redm[tc * 64 + r];
            const int ck = redk[tc * 64 + r];
            if (c1 < bm || (c1 == bm && ck < bk)) { bm = c1; bk = ck; }
        }
        const int t = t0 + r;
        if (t < T_DIM) {
            const unsigned long long pack =
                ((unsigned long long)__float_as_uint(bm) << 32) | (unsigned)bk;
            atomicMin(slots + b * T_DIM + t, pack);
        }
    }
}

// ---------------- kernel D: gather + STE output + indices + loss partials ---
__global__ __launch_bounds__(256) void vq_output(
    const float* __restrict__ x, const float* __restrict__ cb,
    const unsigned long long* __restrict__ slots, float* __restrict__ out,
    float* __restrict__ partials) {
    const int tid = threadIdx.x;
    const int b = blockIdx.y;
    const int t0 = blockIdx.x * OT;
    __shared__ int idxs[OT];
    if (tid < OT) {
        const int t = t0 + tid;
        if (t < T_DIM) {
            const int id = (int)(unsigned)(slots[b * T_DIM + t] & 0xffffffffull);
            idxs[tid] = id;
            out[(size_t)TOTAL_ELEMS + b * T_DIM + t] = (float)id;   // indices
        }
    }
    __syncthreads();
    const int ti = tid & 63;
    const int cq = tid >> 6;       // 0..3
    const int t = t0 + ti;
    float lsum = 0.f;
    if (t < T_DIM) {
        const int id = idxs[ti];
        for (int c0 = 0; c0 < C_DIM; c0 += 4) {
            const int c = c0 + cq;
            const size_t off = (size_t)(b * C_DIM + c) * T_DIM + t;
            const float xv = x[off];
            const float q = cb[(size_t)id * C_DIM + c];
            out[off] = __fadd_rn(xv, __fsub_rn(q, xv));   // STE, np-exact
            const float d = __fsub_rn(q, xv);
            lsum = fmaf(d, d, lsum);
        }
    }
#pragma unroll
    for (int off = 32; off; off >>= 1) lsum += __shfl_down(lsum, off, 64);
    __shared__ float wsum[4];
    if ((tid & 63) == 0) wsum[tid >> 6] = lsum;
    __syncthreads();
    if (tid == 0)
        partials[blockIdx.y * gridDim.x + blockIdx.x] =
            wsum[0] + wsum[1] + wsum[2] + wsum[3];
}

// ---------------- kernel E: final loss reduce -------------------------------
__global__ void vq_loss(const float* __restrict__ partials, int nparts,
                        float* __restrict__ out) {
    __shared__ float red[256];
    float s = 0.f;
    for (int i = threadIdx.x; i < nparts; i += 256) s += partials[i];
    red[threadIdx.x] = s;
    __syncthreads();
    for (int off = 128; off; off >>= 1) {
        if (threadIdx.x < off) red[threadIdx.x] += red[threadIdx.x + off];
        __syncthreads();
    }
    if (threadIdx.x == 0)
        out[(size_t)TOTAL_ELEMS + N_ROWS] = red[0] * (1.0f / (float)TOTAL_ELEMS);
}

// ---------------- launch -----------------------------------------------------
extern "C" void kernel_launch(void* const* d_in, const int* in_sizes, int n_in,
                              void* d_out, int out_size, void* d_ws, size_t ws_size,
                              hipStream_t stream) {
    const float* x = (const float*)d_in[0];
    const float* cb = (const float*)d_in[1];
    float* out = (float*)d_out;

    // xT scratch lives in d_out[0 .. 6144000) (overwritten by vq_output later)
    float* xT = out;

    // ws layout (bytes): Se 8K | Sx 96000 | slots (u64, 8-aligned) | partials
    float* Se = (float*)d_ws;
    float* Sx = Se + K_CODES;
    unsigned long long* slots =
        (unsigned long long*)((char*)d_ws + ((8192 + 96000 + 7) & ~7ull));
    float* partials = (float*)(slots + N_ROWS);

    vq_transpose<<<dim3(47, 8, B_DIM), dim3(256), 0, stream>>>(x, xT);
    vq_se<<<dim3(K_CODES / 256), dim3(256), 0, stream>>>(cb, Se);
    vq_sx<<<dim3((N_ROWS + 255) / 256), dim3(256), 0, stream>>>(xT, Sx);
    vq_init<<<dim3((N_ROWS + 255) / 256), dim3(256), 0, stream>>>(slots);
    vq_argmin<<<dim3((T_DIM + TM - 1) / TM, B_DIM, K_CODES / KSLICE),
                dim3(256), 0, stream>>>(xT, cb, Se, Sx, slots);
    vq_output<<<dim3((T_DIM + OT - 1) / OT, B_DIM), dim3(256), 0, stream>>>(
        x, cb, slots, out, partials);
    vq_loss<<<dim3(1), dim3(256), 0, stream>>>(
        partials, (T_DIM + OT - 1) / OT * B_DIM, out);
}

// Round 6
// 911.728 us; speedup vs baseline: 2.7411x; 2.7411x over previous
//
#include <hip/hip_runtime.h>
#include <stdint.h>

// Vector quantizer, bit-exact emulation of the numpy-f32 reference pipeline:
//   Sx[n] = np.sum(x_flat*x_flat, 1)   (numpy pairwise_sum, n=256)
//   M     = x_flat @ cb.T              (BLAS: sequential FMA over c ascending)
//   dist  = fl(fl(Sx - 2M) + Se),  idx = argmin (first min)
// x (16,256,1500) f32, codebook (2048,256) f32.
// out = [quantized (B,C,T) | indices (B,1,T) as float | loss] f32.
//
// Perf structure (round 6): NO LDS in the hot loop. Round 4's 65% VALUBusy
// was the LDS ds_read_b128 issue ceiling (0.5 B/FLOP = 128 B/cyc/CU needed
// vs ~85 available), not barrier drains. Both operand streams are broadcast
// shaped (8 distinct 16B segments per wave) so direct global loads coalesce
// to 128 B/wave-instr and ride L1/L2 instead of the LDS pipe.

#define B_DIM 16
#define C_DIM 256
#define T_DIM 1500
#define K_CODES 2048
#define N_ROWS (B_DIM * T_DIM)               // 24000
#define TOTAL_ELEMS (B_DIM * C_DIM * T_DIM)  // 6144000

#define TM 64        // t-rows per argmin block
#define KSLICE 256   // codes per block (8 slices -> 3072 blocks, even passes)
#define OT 64        // t per output block

// ---------------- kernel T: x (B,C,T) -> xT (B,T,C) in d_out scratch --------
__global__ __launch_bounds__(256) void vq_transpose(const float* __restrict__ x,
                                                    float* __restrict__ xT) {
    __shared__ float tile[32][33];
    const int b = blockIdx.z;
    const int t0 = blockIdx.x * 32;
    const int c0 = blockIdx.y * 32;
    const int tx = threadIdx.x & 31;
    const int ty = threadIdx.x >> 5;          // 0..7
#pragma unroll
    for (int q = 0; q < 4; ++q) {
        const int c = c0 + ty * 4 + q;
        int t = t0 + tx; if (t >= T_DIM) t = T_DIM - 1;
        tile[ty * 4 + q][tx] = x[((size_t)b * C_DIM + c) * T_DIM + t];
    }
    __syncthreads();
#pragma unroll
    for (int q = 0; q < 4; ++q) {
        const int t = t0 + ty * 4 + q;
        if (t < T_DIM)
            xT[((size_t)b * T_DIM + t) * C_DIM + c0 + tx] = tile[tx][ty * 4 + q];
    }
}

// ---------------- kernel A: Se[k] = np-pairwise sum of cb row squares -------
__global__ __launch_bounds__(256) void vq_se(const float* __restrict__ cb,
                                             float* __restrict__ Se) {
    const int k = blockIdx.x * 256 + threadIdx.x;
    if (k >= K_CODES) return;
    const float* row = cb + (size_t)k * C_DIM;
    float h[2];
#pragma unroll
    for (int half = 0; half < 2; ++half) {
        const float* a = row + half * 128;
        float r[8];
#pragma unroll
        for (int j = 0; j < 8; ++j) r[j] = __fmul_rn(a[j], a[j]);
        for (int i = 8; i < 128; i += 8)
#pragma unroll
            for (int j = 0; j < 8; ++j)
                r[j] = __fadd_rn(r[j], __fmul_rn(a[i + j], a[i + j]));
        h[half] = __fadd_rn(
            __fadd_rn(__fadd_rn(r[0], r[1]), __fadd_rn(r[2], r[3])),
            __fadd_rn(__fadd_rn(r[4], r[5]), __fadd_rn(r[6], r[7])));
    }
    Se[k] = __fadd_rn(h[0], h[1]);
}

// ---------------- kernel B: Sx[n] from xT rows (same pairwise order) --------
__global__ __launch_bounds__(256) void vq_sx(const float* __restrict__ xT,
                                             float* __restrict__ Sx) {
    const int n = blockIdx.x * 256 + threadIdx.x;
    if (n >= N_ROWS) return;
    const float* row = xT + (size_t)n * C_DIM;
    float h[2];
#pragma unroll
    for (int half = 0; half < 2; ++half) {
        const float* a = row + half * 128;
        float r[8];
#pragma unroll
        for (int j = 0; j < 8; ++j) r[j] = __fmul_rn(a[j], a[j]);
        for (int i = 8; i < 128; i += 8)
#pragma unroll
            for (int j = 0; j < 8; ++j)
                r[j] = __fadd_rn(r[j], __fmul_rn(a[i + j], a[i + j]));
        h[half] = __fadd_rn(
            __fadd_rn(__fadd_rn(r[0], r[1]), __fadd_rn(r[2], r[3])),
            __fadd_rn(__fadd_rn(r[4], r[5]), __fadd_rn(r[6], r[7])));
    }
    Sx[n] = __fadd_rn(h[0], h[1]);
}

// ---------------- kernel I: init u64 argmin slots ---------------------------
__global__ void vq_init(unsigned long long* __restrict__ slots) {
    const int n = blockIdx.x * 256 + threadIdx.x;
    if (n < N_ROWS) slots[n] = ~0ull;
}

// ---------------- kernel C: fused GEMM + argmin, no-LDS hot loop ------------
// grid (24 t-tiles, 16 b, 8 k-slices), 256 threads.
// thread (tr=tid&7, tcol=tid>>3): micro-tile 8 rows x 8 codes; operands
// loaded directly from global (broadcast-coalesced, L1-resident per stage).
__global__ __launch_bounds__(256) void vq_argmin(
    const float* __restrict__ xT, const float* __restrict__ cb,
    const float* __restrict__ Se, const float* __restrict__ Sx,
    unsigned long long* __restrict__ slots) {
    __shared__ float redm[32 * 64];     // 8 KB
    __shared__ int   redk[32 * 64];     // 8 KB

    const int tid = threadIdx.x;
    const int t0 = blockIdx.x * TM;
    const int b = blockIdx.y;
    const int k0 = blockIdx.z * KSLICE + (tid >> 3) * 8;  // this thread's code 0
    const int tr = tid & 7;
    const int tcol = tid >> 3;          // 0..31

    // per-row x pointers (clamped rows duplicate t=1499; discarded at merge)
    const float* xr[8];
#pragma unroll
    for (int i = 0; i < 8; ++i) {
        int t = t0 + tr * 8 + i;
        if (t >= T_DIM) t = T_DIM - 1;
        xr[i] = xT + ((size_t)b * T_DIM + t) * C_DIM;
    }
    // cb base pointers for j=0..3 / j=4..7 (imm offsets cover j*1024+g*16)
    const float* cb0 = cb + (size_t)k0 * C_DIM;
    const float* cb4 = cb0 + 4 * C_DIM;

    float acc[8][8];
#pragma unroll
    for (int i = 0; i < 8; ++i)
#pragma unroll
        for (int j = 0; j < 8; ++j) acc[i][j] = 0.f;

#pragma unroll 2
    for (int g = 0; g < 64; ++g) {      // c = 4g .. 4g+3, ascending
        float4 cv[8];
#pragma unroll
        for (int j4 = 0; j4 < 4; ++j4) {
            cv[j4]     = *reinterpret_cast<const float4*>(cb0 + (size_t)j4 * C_DIM + g * 4);
            cv[j4 + 4] = *reinterpret_cast<const float4*>(cb4 + (size_t)j4 * C_DIM + g * 4);
        }
#pragma unroll
        for (int ih = 0; ih < 2; ++ih) {
            float4 xv[4];
#pragma unroll
            for (int ii = 0; ii < 4; ++ii)
                xv[ii] = *reinterpret_cast<const float4*>(xr[ih * 4 + ii] + g * 4);
#pragma unroll
            for (int ii = 0; ii < 4; ++ii) {
                const int i = ih * 4 + ii;
#pragma unroll
                for (int j = 0; j < 8; ++j) {
                    acc[i][j] = fmaf(xv[ii].x, cv[j].x, acc[i][j]);
                    acc[i][j] = fmaf(xv[ii].y, cv[j].y, acc[i][j]);
                    acc[i][j] = fmaf(xv[ii].z, cv[j].z, acc[i][j]);
                    acc[i][j] = fmaf(xv[ii].w, cv[j].w, acc[i][j]);
                }
            }
        }
    }

    // ---- score: dist = fl(fl(Sx - 2*M) + Se); first-min (k ascending)
    float sxr[8];
#pragma unroll
    for (int i = 0; i < 8; ++i) {
        int t = t0 + tr * 8 + i;
        if (t >= T_DIM) t = T_DIM - 1;
        sxr[i] = Sx[b * T_DIM + t];
    }
    float m1[8];
    int k1[8];
#pragma unroll
    for (int i = 0; i < 8; ++i) { m1[i] = 1e30f; k1[i] = 0x7fffffff; }
#pragma unroll
    for (int j = 0; j < 8; ++j) {
        const float ev = Se[k0 + j];
        const int kg = k0 + j;
#pragma unroll
        for (int i = 0; i < 8; ++i) {
            const float s = __fadd_rn(
                __fsub_rn(sxr[i], __fmul_rn(2.0f, acc[i][j])), ev);
            if (s < m1[i]) { m1[i] = s; k1[i] = kg; }
        }
    }

    // ---- cross-thread merge (32 threads per row), transposed layout
#pragma unroll
    for (int i = 0; i < 8; ++i) {
        const int r = tr * 8 + i;
        redm[tcol * 64 + r] = m1[i];
        redk[tcol * 64 + r] = k1[i];
    }
    __syncthreads();
    if (tid < TM) {
        const int r = tid;
        float bm = 1e30f;
        int bk = 0x7fffffff;
        for (int tc = 0; tc < 32; ++tc) {
            const float c1 = redm[tc * 64 + r];
            const int ck = redk[tc * 64 + r];
            if (c1 < bm || (c1 == bm && ck < bk)) { bm = c1; bk = ck; }
        }
        const int t = t0 + r;
        if (t < T_DIM) {
            const unsigned long long pack =
                ((unsigned long long)__float_as_uint(bm) << 32) | (unsigned)bk;
            atomicMin(slots + b * T_DIM + t, pack);
        }
    }
}

// ---------------- kernel D: gather + STE output + indices + loss partials ---
__global__ __launch_bounds__(256) void vq_output(
    const float* __restrict__ x, const float* __restrict__ cb,
    const unsigned long long* __restrict__ slots, float* __restrict__ out,
    float* __restrict__ partials) {
    const int tid = threadIdx.x;
    const int b = blockIdx.y;
    const int t0 = blockIdx.x * OT;
    __shared__ int idxs[OT];
    if (tid < OT) {
        const int t = t0 + tid;
        if (t < T_DIM) {
            const int id = (int)(unsigned)(slots[b * T_DIM + t] & 0xffffffffull);
            idxs[tid] = id;
            out[(size_t)TOTAL_ELEMS + b * T_DIM + t] = (float)id;   // indices
        }
    }
    __syncthreads();
    const int ti = tid & 63;
    const int cq = tid >> 6;       // 0..3
    const int t = t0 + ti;
    float lsum = 0.f;
    if (t < T_DIM) {
        const int id = idxs[ti];
        for (int c0 = 0; c0 < C_DIM; c0 += 4) {
            const int c = c0 + cq;
            const size_t off = (size_t)(b * C_DIM + c) * T_DIM + t;
            const float xv = x[off];
            const float q = cb[(size_t)id * C_DIM + c];
            out[off] = __fadd_rn(xv, __fsub_rn(q, xv));   // STE, np-exact
            const float d = __fsub_rn(q, xv);
            lsum = fmaf(d, d, lsum);
        }
    }
#pragma unroll
    for (int off = 32; off; off >>= 1) lsum += __shfl_down(lsum, off, 64);
    __shared__ float wsum[4];
    if ((tid & 63) == 0) wsum[tid >> 6] = lsum;
    __syncthreads();
    if (tid == 0)
        partials[blockIdx.y * gridDim.x + blockIdx.x] =
            wsum[0] + wsum[1] + wsum[2] + wsum[3];
}

// ---------------- kernel E: final loss reduce -------------------------------
__global__ void vq_loss(const float* __restrict__ partials, int nparts,
                        float* __restrict__ out) {
    __shared__ float red[256];
    float s = 0.f;
    for (int i = threadIdx.x; i < nparts; i += 256) s += partials[i];
    red[threadIdx.x] = s;
    __syncthreads();
    for (int off = 128; off; off >>= 1) {
        if (threadIdx.x < off) red[threadIdx.x] += red[threadIdx.x + off];
        __syncthreads();
    }
    if (threadIdx.x == 0)
        out[(size_t)TOTAL_ELEMS + N_ROWS] = red[0] * (1.0f / (float)TOTAL_ELEMS);
}

// ---------------- launch -----------------------------------------------------
extern "C" void kernel_launch(void* const* d_in, const int* in_sizes, int n_in,
                              void* d_out, int out_size, void* d_ws, size_t ws_size,
                              hipStream_t stream) {
    const float* x = (const float*)d_in[0];
    const float* cb = (const float*)d_in[1];
    float* out = (float*)d_out;

    // xT scratch lives in d_out[0 .. 6144000) (overwritten by vq_output later)
    float* xT = out;

    // ws layout (bytes): Se 8K | Sx 96000 | slots (u64, 8-aligned) | partials
    float* Se = (float*)d_ws;
    float* Sx = Se + K_CODES;
    unsigned long long* slots =
        (unsigned long long*)((char*)d_ws + ((8192 + 96000 + 7) & ~7ull));
    float* partials = (float*)(slots + N_ROWS);

    vq_transpose<<<dim3(47, 8, B_DIM), dim3(256), 0, stream>>>(x, xT);
    vq_se<<<dim3(K_CODES / 256), dim3(256), 0, stream>>>(cb, Se);
    vq_sx<<<dim3((N_ROWS + 255) / 256), dim3(256), 0, stream>>>(xT, Sx);
    vq_init<<<dim3((N_ROWS + 255) / 256), dim3(256), 0, stream>>>(slots);
    vq_argmin<<<dim3((T_DIM + TM - 1) / TM, B_DIM, K_CODES / KSLICE),
                dim3(256), 0, stream>>>(xT, cb, Se, Sx, slots);
    vq_output<<<dim3((T_DIM + OT - 1) / OT, B_DIM), dim3(256), 0, stream>>>(
        x, cb, slots, out, partials);
    vq_loss<<<dim3(1), dim3(256), 0, stream>>>(
        partials, (T_DIM + OT - 1) / OT * B_DIM, out);
}

// Round 7
// 512.571 us; speedup vs baseline: 4.8757x; 1.7787x over previous
//
#include <hip/hip_runtime.h>
#include <stdint.h>

// Vector quantizer, bit-exact emulation of the numpy-f32 reference pipeline:
//   Sx[n] = np.sum(x_flat*x_flat, 1)   (numpy pairwise_sum, n=256)
//   M     = x_flat @ cb.T              (BLAS: sequential FMA over c ascending)
//   dist  = fl(fl(Sx - 2M) + Se),  idx = argmin (first min)
// x (16,256,1500) f32, codebook (2048,256) f32.
// out = [quantized (B,C,T) | indices (B,1,T) as float | loss] f32.
//
// Round 7 structure: row-per-lane. Each lane owns one t-row; the 8 codes a
// wave processes at a time are WAVE-UNIFORM, so cb streams through the
// scalar (SMEM) pipe into SGPRs and feeds v_fma as the SGPR operand.
// Only x touches LDS: one ds_read_b128 per 32 FMAs (0.5 B/FMA vs round 4's
// 1.0) -> LDS pipe ~75% util, VALU becomes the binding resource.
// No barriers in the hot loop; 16 waves/CU hide the lgkm drains.

#define B_DIM 16
#define C_DIM 256
#define T_DIM 1500
#define K_CODES 2048
#define N_ROWS (B_DIM * T_DIM)               // 24000
#define TOTAL_ELEMS (B_DIM * C_DIM * T_DIM)  // 6144000

#define WPB 8         // waves per block
#define TKW 64        // codes per wave
#define KSLICE (WPB * TKW)   // 512 codes per block -> 4 k-slices
#define XPITCH 260    // floats per LDS x row (16B pad -> 2-way bank alias, free)
#define OT 64         // t per output block

__device__ __forceinline__ void gl_lds16(const float* g, float* l) {
    __builtin_amdgcn_global_load_lds(
        (const __attribute__((address_space(1))) void*)(uintptr_t)g,
        (__attribute__((address_space(3))) void*)(uintptr_t)l, 16, 0, 0);
}

// ---------------- kernel T: x (B,C,T) -> xT (B,T,C) in d_out scratch --------
__global__ __launch_bounds__(256) void vq_transpose(const float* __restrict__ x,
                                                    float* __restrict__ xT) {
    __shared__ float tile[32][33];
    const int b = blockIdx.z;
    const int t0 = blockIdx.x * 32;
    const int c0 = blockIdx.y * 32;
    const int tx = threadIdx.x & 31;
    const int ty = threadIdx.x >> 5;          // 0..7
#pragma unroll
    for (int q = 0; q < 4; ++q) {
        const int c = c0 + ty * 4 + q;
        int t = t0 + tx; if (t >= T_DIM) t = T_DIM - 1;
        tile[ty * 4 + q][tx] = x[((size_t)b * C_DIM + c) * T_DIM + t];
    }
    __syncthreads();
#pragma unroll
    for (int q = 0; q < 4; ++q) {
        const int t = t0 + ty * 4 + q;
        if (t < T_DIM)
            xT[((size_t)b * T_DIM + t) * C_DIM + c0 + tx] = tile[tx][ty * 4 + q];
    }
}

// ---------------- kernel A: Se[k] = np-pairwise sum of cb row squares -------
__global__ __launch_bounds__(256) void vq_se(const float* __restrict__ cb,
                                             float* __restrict__ Se) {
    const int k = blockIdx.x * 256 + threadIdx.x;
    if (k >= K_CODES) return;
    const float* row = cb + (size_t)k * C_DIM;
    float h[2];
#pragma unroll
    for (int half = 0; half < 2; ++half) {
        const float* a = row + half * 128;
        float r[8];
#pragma unroll
        for (int j = 0; j < 8; ++j) r[j] = __fmul_rn(a[j], a[j]);
        for (int i = 8; i < 128; i += 8)
#pragma unroll
            for (int j = 0; j < 8; ++j)
                r[j] = __fadd_rn(r[j], __fmul_rn(a[i + j], a[i + j]));
        h[half] = __fadd_rn(
            __fadd_rn(__fadd_rn(r[0], r[1]), __fadd_rn(r[2], r[3])),
            __fadd_rn(__fadd_rn(r[4], r[5]), __fadd_rn(r[6], r[7])));
    }
    Se[k] = __fadd_rn(h[0], h[1]);
}

// ---------------- kernel B: Sx[n] from xT rows (same pairwise order) --------
__global__ __launch_bounds__(256) void vq_sx(const float* __restrict__ xT,
                                             float* __restrict__ Sx) {
    const int n = blockIdx.x * 256 + threadIdx.x;
    if (n >= N_ROWS) return;
    const float* row = xT + (size_t)n * C_DIM;
    float h[2];
#pragma unroll
    for (int half = 0; half < 2; ++half) {
        const float* a = row + half * 128;
        float r[8];
#pragma unroll
        for (int j = 0; j < 8; ++j) r[j] = __fmul_rn(a[j], a[j]);
        for (int i = 8; i < 128; i += 8)
#pragma unroll
            for (int j = 0; j < 8; ++j)
                r[j] = __fadd_rn(r[j], __fmul_rn(a[i + j], a[i + j]));
        h[half] = __fadd_rn(
            __fadd_rn(__fadd_rn(r[0], r[1]), __fadd_rn(r[2], r[3])),
            __fadd_rn(__fadd_rn(r[4], r[5]), __fadd_rn(r[6], r[7])));
    }
    Sx[n] = __fadd_rn(h[0], h[1]);
}

// ---------------- kernel I: init u64 argmin slots ---------------------------
__global__ void vq_init(unsigned long long* __restrict__ slots) {
    const int n = blockIdx.x * 256 + threadIdx.x;
    if (n < N_ROWS) slots[n] = ~0ull;
}

// ---------------- kernel C: fused GEMM + argmin (bit-exact np-f32) ----------
// grid (24 t-tiles, 16 b, 4 k-slices), 512 threads = 8 waves.
// Lane owns row t0+lane (shared x tile in LDS); wave w owns codes
// [k0 + w*64, +64), processed 8 at a time from SGPRs.
__global__ __launch_bounds__(512) void vq_argmin(
    const float* __restrict__ xT, const float* __restrict__ cb,
    const float* __restrict__ Se, const float* __restrict__ Sx,
    unsigned long long* __restrict__ slots) {
    __shared__ float xs[64 * XPITCH];   // 66560 B
    __shared__ float redm[WPB * 64];    // 2 KB
    __shared__ int   redk[WPB * 64];    // 2 KB

    const int tid = threadIdx.x;
    const int wid = tid >> 6;
    const int lane = tid & 63;
    const int t0 = blockIdx.x * 64;
    const int b = blockIdx.y;
    const int k0 = blockIdx.z * KSLICE;

    const float* xTb = xT + (size_t)b * T_DIM * C_DIM;

    // ---- stage 64 x rows into LDS (wave w loads rows w*8..w*8+7)
#pragma unroll
    for (int i = 0; i < 8; ++i) {
        const int r = wid * 8 + i;
        int t = t0 + r; if (t >= T_DIM) t = T_DIM - 1;     // dup, discarded
        gl_lds16(xTb + (size_t)t * C_DIM + lane * 4, &xs[r * XPITCH]);
    }
    __syncthreads();

    int trow = t0 + lane; if (trow >= T_DIM) trow = T_DIM - 1;
    const float sxv = Sx[b * T_DIM + trow];
    const float* xrow = xs + lane * XPITCH;

    // wave-uniform cb/Se bases (readfirstlane forces SGPR -> scalar loads)
    const int kw0 = __builtin_amdgcn_readfirstlane(k0 + wid * TKW);
    const float* cbw = cb + (size_t)kw0 * C_DIM;
    const float* sew = Se + kw0;

    float m1 = 1e30f;
    int k1 = 0x7fffffff;

#pragma unroll 1
    for (int kk = 0; kk < TKW / 8; ++kk) {       // 8 chunks of 8 codes
        const float* cbc = cbw + (size_t)kk * 8 * C_DIM;
        float acc[8];
#pragma unroll
        for (int j = 0; j < 8; ++j) acc[j] = 0.f;

#pragma unroll 2
        for (int g = 0; g < 64; ++g) {           // c = 4g..4g+3 ascending
            const float4 xv = *reinterpret_cast<const float4*>(xrow + g * 4);
#pragma unroll
            for (int j = 0; j < 8; ++j) {
                const float4 cv = *reinterpret_cast<const float4*>(
                    cbc + (size_t)j * C_DIM + g * 4);    // uniform -> s_load
                acc[j] = fmaf(xv.x, cv.x, acc[j]);
                acc[j] = fmaf(xv.y, cv.y, acc[j]);
                acc[j] = fmaf(xv.z, cv.z, acc[j]);
                acc[j] = fmaf(xv.w, cv.w, acc[j]);
            }
        }
        // score: dist = fl(fl(Sx - 2*M) + Se); first-min (k ascending)
#pragma unroll
        for (int j = 0; j < 8; ++j) {
            const float se = sew[kk * 8 + j];            // uniform
            const float s = __fadd_rn(
                __fsub_rn(sxv, __fmul_rn(2.0f, acc[j])), se);
            if (s < m1) { m1 = s; k1 = kw0 + kk * 8 + j; }
        }
    }

    // ---- cross-wave merge (8 waves per row)
    redm[wid * 64 + lane] = m1;
    redk[wid * 64 + lane] = k1;
    __syncthreads();
    if (tid < 64) {
        float bm = 1e30f;
        int bk = 0x7fffffff;
#pragma unroll
        for (int w = 0; w < WPB; ++w) {          // w ascending = k ascending
            const float c1 = redm[w * 64 + tid];
            const int ck = redk[w * 64 + tid];
            if (c1 < bm) { bm = c1; bk = ck; }
        }
        const int t = t0 + tid;
        if (t < T_DIM) {
            const unsigned long long pack =
                ((unsigned long long)__float_as_uint(bm) << 32) | (unsigned)bk;
            atomicMin(slots + b * T_DIM + t, pack);
        }
    }
}

// ---------------- kernel D: gather + STE output + indices + loss partials ---
__global__ __launch_bounds__(256) void vq_output(
    const float* __restrict__ x, const float* __restrict__ cb,
    const unsigned long long* __restrict__ slots, float* __restrict__ out,
    float* __restrict__ partials) {
    const int tid = threadIdx.x;
    const int b = blockIdx.y;
    const int t0 = blockIdx.x * OT;
    __shared__ int idxs[OT];
    if (tid < OT) {
        const int t = t0 + tid;
        if (t < T_DIM) {
            const int id = (int)(unsigned)(slots[b * T_DIM + t] & 0xffffffffull);
            idxs[tid] = id;
            out[(size_t)TOTAL_ELEMS + b * T_DIM + t] = (float)id;   // indices
        }
    }
    __syncthreads();
    const int ti = tid & 63;
    const int cq = tid >> 6;       // 0..3
    const int t = t0 + ti;
    float lsum = 0.f;
    if (t < T_DIM) {
        const int id = idxs[ti];
        for (int c0 = 0; c0 < C_DIM; c0 += 4) {
            const int c = c0 + cq;
            const size_t off = (size_t)(b * C_DIM + c) * T_DIM + t;
            const float xv = x[off];
            const float q = cb[(size_t)id * C_DIM + c];
            out[off] = __fadd_rn(xv, __fsub_rn(q, xv));   // STE, np-exact
            const float d = __fsub_rn(q, xv);
            lsum = fmaf(d, d, lsum);
        }
    }
#pragma unroll
    for (int off = 32; off; off >>= 1) lsum += __shfl_down(lsum, off, 64);
    __shared__ float wsum[4];
    if ((tid & 63) == 0) wsum[tid >> 6] = lsum;
    __syncthreads();
    if (tid == 0)
        partials[blockIdx.y * gridDim.x + blockIdx.x] =
            wsum[0] + wsum[1] + wsum[2] + wsum[3];
}

// ---------------- kernel E: final loss reduce -------------------------------
__global__ void vq_loss(const float* __restrict__ partials, int nparts,
                        float* __restrict__ out) {
    __shared__ float red[256];
    float s = 0.f;
    for (int i = threadIdx.x; i < nparts; i += 256) s += partials[i];
    red[threadIdx.x] = s;
    __syncthreads();
    for (int off = 128; off; off >>= 1) {
        if (threadIdx.x < off) red[threadIdx.x] += red[threadIdx.x + off];
        __syncthreads();
    }
    if (threadIdx.x == 0)
        out[(size_t)TOTAL_ELEMS + N_ROWS] = red[0] * (1.0f / (float)TOTAL_ELEMS);
}

// ---------------- launch -----------------------------------------------------
extern "C" void kernel_launch(void* const* d_in, const int* in_sizes, int n_in,
                              void* d_out, int out_size, void* d_ws, size_t ws_size,
                              hipStream_t stream) {
    const float* x = (const float*)d_in[0];
    const float* cb = (const float*)d_in[1];
    float* out = (float*)d_out;

    // xT scratch lives in d_out[0 .. 6144000) (overwritten by vq_output later)
    float* xT = out;

    // ws layout (bytes): Se 8K | Sx 96000 | slots (u64, 8-aligned) | partials
    float* Se = (float*)d_ws;
    float* Sx = Se + K_CODES;
    unsigned long long* slots =
        (unsigned long long*)((char*)d_ws + ((8192 + 96000 + 7) & ~7ull));
    float* partials = (float*)(slots + N_ROWS);

    vq_transpose<<<dim3(47, 8, B_DIM), dim3(256), 0, stream>>>(x, xT);
    vq_se<<<dim3(K_CODES / 256), dim3(256), 0, stream>>>(cb, Se);
    vq_sx<<<dim3((N_ROWS + 255) / 256), dim3(256), 0, stream>>>(xT, Sx);
    vq_init<<<dim3((N_ROWS + 255) / 256), dim3(256), 0, stream>>>(slots);
    vq_argmin<<<dim3((T_DIM + 63) / 64, B_DIM, K_CODES / KSLICE),
                dim3(512), 0, stream>>>(xT, cb, Se, Sx, slots);
    vq_output<<<dim3((T_DIM + OT - 1) / OT, B_DIM), dim3(256), 0, stream>>>(
        x, cb, slots, out, partials);
    vq_loss<<<dim3(1), dim3(256), 0, stream>>>(
        partials, (T_DIM + OT - 1) / OT * B_DIM, out);
}